// Round 9
// baseline (321.820 us; speedup 1.0000x reference)
//
#include <hip/hip_runtime.h>
#include <hip/hip_bf16.h>
#include <cstdint>

// SelfAttention: B=8, S=2048, D_IN=D_OUT=768, fp32 in/out.
// R17 = R16 resubmitted verbatim (R8 bench was an infra failure: container
// died twice, no signal). See R16 notes below.
// R16 = R13 base (preprocess cvt + all-global_load_lds GEMMs, QKV XCD
// swizzle) with the MFMA shape swapped 16x16x32 -> 32x32x16.
// R14/R15 post-mortem: fused x->bf16 cvt into QKV (both serial and
// T14-pipelined reg-stage) regressed QKV 70->103/109us — reg-staging loses
// ~16% vs global_load_lds and doubles A fetch. Fusion arc closed; R13
// staging restored.
// R16 rationale: per-CU K-step budget (scores): LDS ~3000cyc, MFMA ~1920cyc
// @3277 FLOP/cyc (16x16), wall 5240cyc. 32x32x16 runs 4096 FLOP/cyc
// (m119: 2495 vs 2176 TF) and halves MFMA issues (16x8cyc=129 vs
// 32x5cyc=160 per wave per K-step). Same LDS bytes/swizzle/staging.
// A-frag mapping: lane l -> A[l&31][(l>>5)*8 + i] (family analogy of the
// verified 16x16x32 mapping); C/D: col=lane&31, row=(reg&3)+8*(reg>>2)
// +4*(lane>>5) [m74/m101 HW-verified]. Epilogues re-indexed accordingly.
// Structure: 4 kernels — preprocess (x->bf16, Wt=bf16(W^T), rowsum=0),
// QKV GEMM (Q|K -> qkvb, V -> vt via epilogue transpose), scores GEMM
// (E=exp(scale*QK^T) bf16 + fp32 rowsum atomics), PV GEMM (out=(E@V)/rowsum).
// ws: xb 25.2M | Wt 3.5M | qkvb(QK) 50.3M | vt 25.2M | probs(E) 67.1M | rowsum 64K

#define NB 8
#define NS 2048
#define ND 768
#define NQK 1536   // qkvb row width (Q|K only)
#define MTOT 16384 // NB*NS

using f32x4  = __attribute__((ext_vector_type(4))) float;
using f32x16 = __attribute__((ext_vector_type(16))) float;
using s16x8  = __attribute__((ext_vector_type(8))) short;

struct alignas(16) bf16x8 { __hip_bfloat16 h[8]; };
struct alignas(8)  bf16x4 { __hip_bfloat16 h[4]; };

// ---------------- preprocess: convert x, transpose W, zero rowsum ----------------
#define CVT_BLOCKS 4096
#define WT_BLOCKS 1728
__global__ __launch_bounds__(256) void preprocess_kernel(const float* __restrict__ x,
                                                         __hip_bfloat16* __restrict__ xb,
                                                         const float* __restrict__ W,
                                                         __hip_bfloat16* __restrict__ Wt,
                                                         float* __restrict__ rowsum) {
    __shared__ float tile[32][33];
    const int tid = threadIdx.x;
    if (blockIdx.x < CVT_BLOCKS) {
#pragma unroll
        for (int it = 0; it < 3; ++it) {
            const int i = (it * CVT_BLOCKS + blockIdx.x) * 256 + tid;
            const f32x4 v = __builtin_nontemporal_load((const f32x4*)x + i);
            bf16x4 o;
            o.h[0] = __float2bfloat16(v[0]);
            o.h[1] = __float2bfloat16(v[1]);
            o.h[2] = __float2bfloat16(v[2]);
            o.h[3] = __float2bfloat16(v[3]);
            ((bf16x4*)xb)[i] = o;
        }
    } else if (blockIdx.x < CVT_BLOCKS + WT_BLOCKS) {
        const int bid = blockIdx.x - CVT_BLOCKS;       // 0..1727 = 3*24*24
        const int e = bid / 576, rem = bid % 576;
        const int k0 = (rem / 24) * 32, n0 = (rem % 24) * 32;
        const float* Wp = W + (size_t)e * ND * ND;
        __hip_bfloat16* Wo = Wt + (size_t)e * ND * ND;
        {   // load 32x32 via float4: ty=row (32), tx=float4-col (8)
            const int ty = tid >> 3, tx = tid & 7;
            const f32x4 v = __builtin_nontemporal_load(
                (const f32x4*)&Wp[(k0 + ty) * ND + n0 + tx * 4]);
#pragma unroll
            for (int q = 0; q < 4; ++q) tile[ty][tx * 4 + q] = v[q];
        }
        __syncthreads();
        {   // store transposed: np=out row (32), kq=k-quad (8)
            const int np = tid >> 3, kq = tid & 7;
            bf16x4 o;
#pragma unroll
            for (int q = 0; q < 4; ++q) o.h[q] = __float2bfloat16(tile[kq * 4 + q][np]);
            *(bf16x4*)&Wo[(long)(n0 + np) * ND + k0 + kq * 4] = o;
        }
    } else {
        const int i = (blockIdx.x - CVT_BLOCKS - WT_BLOCKS) * 1024 + tid * 4;
        f32x4 z = {0.f, 0.f, 0.f, 0.f};
        *(f32x4*)(rowsum + i) = z;
    }
}

// ---------------- MFMA GEMM: C[m][n] = epilogue( sum_k A[m][k]*B[n][k] ) ----------------
// 128x128 tile, BK=64, 4 waves, 2x2 32x32x16 MFMAs/wave (4 k-subtiles),
// global_load_lds width=16 staging, XOR-swizzled LDS.
// EPI 2: QKV split (tileN<1536 -> bf16 C; else transpose tile -> vt[b][d][s])
// EPI 3: scores    (store bf16 exp(scale*acc), atomicAdd fp32 row sums)
// EPI 4: PV        (f32 C scaled by 1/rowsum[row])
__device__ __forceinline__ void storeC(float* p, float v) { *p = v; }
__device__ __forceinline__ void storeC(__hip_bfloat16* p, float v) { *p = __float2bfloat16(v); }

template <typename OutT, int EPI, bool BATCH_X>
__global__ __launch_bounds__(256, 3) void gemm_bt_kernel(
    const __hip_bfloat16* __restrict__ A,   // [M][lda], k-contiguous
    const __hip_bfloat16* __restrict__ Bm,  // [N][ldb], k-contiguous
    OutT* __restrict__ C,                   // [M][ldc]
    __hip_bfloat16* __restrict__ vtOut,     // EPI==2
    float* __restrict__ rowsum,             // EPI==3 (accumulate) / EPI==4 (read)
    int K, int lda, int ldb, int ldc,
    long sA, long sB, long sC, float scale) {
    __shared__ char smem[32768];
    char* AsB = smem;
    char* BsB = smem + 16384;

    int b, tileM, tileN;
    if (BATCH_X) {  // batch on x => batch == linear%8 == XCD id (L2 locality)
        b = blockIdx.x; tileN = blockIdx.y * 128; tileM = blockIdx.z * 128;
    } else {        // single batch (QKV): bijective XCD swizzle, 8-M-tile chunks
        b = 0;      // nwg=2304: XCD i gets 288 tiles in two M-contiguous chunks
        const int l0 = blockIdx.y * gridDim.x + blockIdx.x;
        const int i8 = l0 & 7, h = l0 >> 3;            // h in [0,288)
        const int swz = i8 * 144 + (h % 144) + (h / 144) * 1152;
        tileN = (swz % gridDim.x) * 128;               // gridDim.x = 18
        tileM = (swz / gridDim.x) * 128;
    }
    A  += (long)b * sA;
    Bm += (long)b * sB;
    C  += (long)b * sC;

    const int tid  = threadIdx.x;
    const int lane = tid & 63;
    const int wave = tid >> 6;
    const int wm = (wave >> 1) * 64;
    const int wn = (wave & 1) * 64;
    const int l31 = lane & 31;   // row/col within 32x32 tile
    const int hi  = lane >> 5;   // k-half selector (and +4 row offset in C/D)

    // staging: thread covers 16B; row = tid>>3 (0..31), swizzled col chunk
    const int srow = tid >> 3;
    const int scol = ((tid & 7) ^ (srow & 7)) << 3;

    f32x16 acc[2][2];
#pragma unroll
    for (int i = 0; i < 2; ++i)
#pragma unroll
        for (int j = 0; j < 2; ++j)
#pragma unroll
            for (int r = 0; r < 16; ++r) acc[i][j][r] = 0.f;

    const __hip_bfloat16* gA = A + (long)(tileM + srow) * lda + scol;
    const __hip_bfloat16* gB = Bm + (long)(tileN + srow) * ldb + scol;
    const int ldsOff = tid * 16;  // bytes; dest = wave-uniform base + lane*16

    typedef const __attribute__((address_space(1))) void* gp;
    typedef __attribute__((address_space(3))) void* sp;

    const int swa = (l31 & 7) << 4;  // XOR byte swizzle for fragment reads

    for (int k0 = 0; k0 < K; k0 += 64) {
        __syncthreads();
#pragma unroll
        for (int j = 0; j < 4; ++j)
            __builtin_amdgcn_global_load_lds((gp)(gA + (long)(j * 32) * lda + k0),
                                             (sp)(AsB + j * 4096 + ldsOff), 16, 0, 0);
#pragma unroll
        for (int j = 0; j < 4; ++j)
            __builtin_amdgcn_global_load_lds((gp)(gB + (long)(j * 32) * ldb + k0),
                                             (sp)(BsB + j * 4096 + ldsOff), 16, 0, 0);
        __syncthreads();

#pragma unroll
        for (int t = 0; t < 4; ++t) {   // 4 k-subtiles of 16
            const int ck = ((((t << 1) | hi) << 4) ^ swa);
            s16x8 af[2], bfr[2];
#pragma unroll
            for (int mi = 0; mi < 2; ++mi)
                af[mi] = *(const s16x8*)(AsB + (wm + mi * 32 + l31) * 128 + ck);
#pragma unroll
            for (int nj = 0; nj < 2; ++nj)
                bfr[nj] = *(const s16x8*)(BsB + (wn + nj * 32 + l31) * 128 + ck);
#pragma unroll
            for (int mi = 0; mi < 2; ++mi)
#pragma unroll
                for (int nj = 0; nj < 2; ++nj)
                    acc[mi][nj] = __builtin_amdgcn_mfma_f32_32x32x16_bf16(
                        af[mi], bfr[nj], acc[mi][nj], 0, 0, 0);
        }
    }

    // ---------------- epilogues ----------------
    // C/D mapping (32x32): col = l31, row = (reg&3) + 8*(reg>>2) + 4*hi
    if (EPI == 2 && tileN >= NQK) {
        // V tile: transpose through LDS, store to vt[b'][d][s].
        __syncthreads();
        char* T = smem;  // 32KB scratch
#pragma unroll
        for (int mi = 0; mi < 2; ++mi) {
#pragma unroll
            for (int nj = 0; nj < 2; ++nj) {
                const int d = wn + nj * 32 + l31;        // local col (V feature)
#pragma unroll
                for (int q = 0; q < 4; ++q) {            // row granule of 4
                    const int s = wm + mi * 32 + q * 8 + hi * 4;
                    bf16x4 g;
#pragma unroll
                    for (int r = 0; r < 4; ++r) g.h[r] = __float2bfloat16(acc[mi][nj][(q << 2) | r]);
                    const int c = s >> 3;
                    const int off = d * 256 + (((c ^ (d & 15)) << 4) | ((s & 4) << 1));
                    *(bf16x4*)(T + off) = g;
                }
            }
        }
        __syncthreads();
        const int dl = tid >> 1, half = tid & 1;
        const long bb = tileM >> 11;
        const int s0 = tileM & (NS - 1);
        const long dg = (long)(tileN - NQK) + dl;
        __hip_bfloat16* dst = vtOut + (bb * ND + dg) * NS + s0;
#pragma unroll
        for (int cc = 0; cc < 8; ++cc) {
            const int c2 = half * 8 + cc;
            s16x8 val = *(const s16x8*)(T + dl * 256 + ((c2 ^ (dl & 15)) << 4));
            *(s16x8*)(dst + c2 * 8) = val;
        }
        return;
    }

    if (EPI == 3) {
        // scores: store unnormalized E = exp(scale*acc) bf16; row-sum atomics.
        // Sum uses the bf16-ROUNDED values so normalization matches PV's input.
#pragma unroll
        for (int mi = 0; mi < 2; ++mi) {
#pragma unroll
            for (int reg = 0; reg < 16; ++reg) {
                const int row = tileM + wm + mi * 32 + (reg & 3) + 8 * (reg >> 2) + 4 * hi;
                float rs = 0.f;
#pragma unroll
                for (int nj = 0; nj < 2; ++nj) {
                    const int col = tileN + wn + nj * 32 + l31;
                    const float e = __expf(acc[mi][nj][reg] * scale);  // |logit|<~2.5: safe
                    const __hip_bfloat16 h = __float2bfloat16(e);
                    storeC(C + (long)row * ldc + col, __bfloat162float(h));
                    rs += __bfloat162float(h);
                }
                // reduce across the 32 lanes sharing this row (same hi-half)
#pragma unroll
                for (int off = 1; off < 32; off <<= 1) rs += __shfl_xor(rs, off);
                if (l31 == 0) atomicAdd(rowsum + (long)b * NS + row, rs);
            }
        }
        return;
    }

    if (EPI == 4) {
        // PV: normalize by row sum.
#pragma unroll
        for (int mi = 0; mi < 2; ++mi) {
            float inv[16];
#pragma unroll
            for (int reg = 0; reg < 16; ++reg) {
                const int row = tileM + wm + mi * 32 + (reg & 3) + 8 * (reg >> 2) + 4 * hi;
                inv[reg] = 1.0f / rowsum[(long)b * NS + row];
            }
#pragma unroll
            for (int nj = 0; nj < 2; ++nj) {
                const int col = tileN + wn + nj * 32 + l31;
#pragma unroll
                for (int reg = 0; reg < 16; ++reg) {
                    const int row = tileM + wm + mi * 32 + (reg & 3) + 8 * (reg >> 2) + 4 * hi;
                    storeC(C + (long)row * ldc + col, acc[mi][nj][reg] * inv[reg]);
                }
            }
        }
        return;
    }

    // EPI==2 Q|K path: plain bf16 store
#pragma unroll
    for (int mi = 0; mi < 2; ++mi) {
#pragma unroll
        for (int nj = 0; nj < 2; ++nj) {
            const int col = tileN + wn + nj * 32 + l31;
#pragma unroll
            for (int reg = 0; reg < 16; ++reg) {
                const int row = tileM + wm + mi * 32 + (reg & 3) + 8 * (reg >> 2) + 4 * hi;
                storeC(C + (long)row * ldc + col, acc[mi][nj][reg] * scale);
            }
        }
    }
}

// ---------------- launch ----------------
extern "C" void kernel_launch(void* const* d_in, const int* in_sizes, int n_in,
                              void* d_out, int out_size, void* d_ws, size_t ws_size,
                              hipStream_t stream) {
    const float* x   = (const float*)d_in[0];  // [8][2048][768]
    const float* QKV = (const float*)d_in[1];  // [3][768][768]
    float* out = (float*)d_out;                // [8][2048][768]

    uint8_t* ws = (uint8_t*)d_ws;
    constexpr size_t XB_BYTES  = (size_t)MTOT * ND * 2;     // 25.2M
    constexpr size_t WT_BYTES  = (size_t)3 * ND * ND * 2;   //  3.5M
    constexpr size_t QKV_BYTES = (size_t)MTOT * NQK * 2;    // 50.3M (Q|K only)
    constexpr size_t VT_BYTES  = (size_t)NB * ND * NS * 2;  // 25.2M
    constexpr size_t PR_BYTES  = (size_t)MTOT * NS * 2;     // 67.1M
    __hip_bfloat16* xb    = (__hip_bfloat16*)(ws);
    __hip_bfloat16* Wt    = (__hip_bfloat16*)(ws + XB_BYTES);
    __hip_bfloat16* qkvb  = (__hip_bfloat16*)(ws + XB_BYTES + WT_BYTES);
    __hip_bfloat16* vt    = (__hip_bfloat16*)(ws + XB_BYTES + WT_BYTES + QKV_BYTES);
    __hip_bfloat16* probs = (__hip_bfloat16*)(ws + XB_BYTES + WT_BYTES + QKV_BYTES + VT_BYTES);
    float*          rowsum= (float*)(ws + XB_BYTES + WT_BYTES + QKV_BYTES + VT_BYTES + PR_BYTES);

    const float scale = 0.03608439182435161f;  // 1/sqrt(768)

    // 1. preprocess: xb = bf16(x); Wt = bf16(W^T); rowsum = 0
    preprocess_kernel<<<CVT_BLOCKS + WT_BLOCKS + 16, 256, 0, stream>>>(x, xb, QKV, Wt, rowsum);
    // 2. fused QKV projection: Q|K -> qkvb [16384][1536]; V -> vt[b][d][s]
    gemm_bt_kernel<__hip_bfloat16, 2, false><<<dim3(2304 / 128, MTOT / 128, 1), 256, 0, stream>>>(
        xb, Wt, qkvb, vt, nullptr, ND, ND, ND, NQK, 0, 0, 0, 1.0f);
    // 3. E = exp(scale * Q K^T), rowsum += (per batch; batch on x for XCD-L2 locality)
    gemm_bt_kernel<__hip_bfloat16, 3, true><<<dim3(NB, NS / 128, NS / 128), 256, 0, stream>>>(
        qkvb, qkvb + ND, probs, nullptr, rowsum, ND, NQK, NQK, NS,
        (long)NS * NQK, (long)NS * NQK, (long)NS * NS, scale);
    // 4. out = (E @ V) / rowsum  (fp32 out)
    gemm_bt_kernel<float, 4, true><<<dim3(NB, ND / 128, NS / 128), 256, 0, stream>>>(
        probs, vt, out, nullptr, rowsum, NS, NS, NS, ND,
        (long)NS * NS, (long)ND * NS, (long)NS * ND, 1.0f);
}